// Round 16
// baseline (468.881 us; speedup 1.0000x reference)
//
#include <hip/hip_runtime.h>

// Stream_PreNet as ONE composed 7x7 conv (exact algebra, proven R11-R15),
// mfma_f32_32x32x16_bf16, plain stores (NT caused 2x write amplification).
// R16 = R15 + (a) th-major weight layout: phase = kernel row th; slice s2
// covers tw=2s2+hi; no runtime /7, B-base advances by ROWSTR per phase;
// s2=3 B-offset is constant tw=6 (hi=1 half has zero weights). 
// (b) ping-pong weight double-buffer (wa/wb, 4 frags each): next phase's
// 4 L2 loads fly under current phase's 16 MFMA + 16 ds_read -> the per-phase
// latency stall (R14->R15 isolated it) is hidden. Unroll-1 pair loop with
// named buffers = real WAR deps, no hoist-all (R12 disease guard).
// Geometry: block = 32 pix x 16 rows x 96 ch; 6 waves = 3 ch-tiles x 2 row-grps;
// 2 subs x 4 rows; acc = 4x f32x16 (AGPR). Layouts (m74/m101): A[m=ch][k=8hi+j];
// B[k][n=pix l31]; D col=l31, row=(reg&3)+8(reg>>2)+4hi.
// d_ws: wct (96*448 bf16 = 86,016B) + bias2e (96 f32) = 86,400 B.

#define B_   8
#define H_   512
#define W_   256
#define CIN  8
#define COUT 96
#define TH   16           // output rows per block
#define TW   32           // output cols per block
#define RS   (TH + 6)     // 22 staged x rows
#define XC   (TW + 6)     // 38 staged x cols
#define KP   448          // 7 th-phases x 64 (56 real + 8 pad per th)
#define NTHREADS 384      // 6 waves

typedef __bf16 bf16x8 __attribute__((ext_vector_type(8)));
typedef float  f32x4  __attribute__((ext_vector_type(4)));
typedef float  f32x16 __attribute__((ext_vector_type(16)));
typedef int    i32x4  __attribute__((ext_vector_type(4)));

__device__ __forceinline__ unsigned short f2bf(float f) {
  unsigned u = __builtin_bit_cast(unsigned, f);
  u += 0x7FFFu + ((u >> 16) & 1u);   // RNE
  return (unsigned short)(u >> 16);
}

__device__ __forceinline__ bf16x8 ld16s(const unsigned short* p) {
  i32x4 t = *(const i32x4*)p;        // 16B load -> ds_read_b128 / dwordx4
  return __builtin_bit_cast(bf16x8, t);
}

__device__ __forceinline__ f32x16 mfma32(bf16x8 a, bf16x8 b, f32x16 c) {
  return __builtin_amdgcn_mfma_f32_32x32x16_bf16(a, b, c, 0, 0, 0);
}

// jnp.pad mode='symmetric': -1->0, -2->1 ; N->N-1, N+1->N-2
__device__ __forceinline__ int symH(int i) { return i < 0 ? -1 - i : (i >= H_ ? 2 * H_ - 1 - i : i); }
__device__ __forceinline__ int symW(int i) { return i < 0 ? -1 - i : (i >= W_ ? 2 * W_ - 1 - i : i); }

// ---- prep: compose Wc = W2(7x1) o W1(1x7), th-major layout ----
// wct[n][kk], kk = th*64 + tw*8 + c (tw==7 slot zero).  bias2e = b2 + fold(b1).
__global__ void prep_kernel(const float* __restrict__ W1, const float* __restrict__ b1,
                            const float* __restrict__ W2, const float* __restrict__ b2,
                            unsigned short* __restrict__ wct, float* __restrict__ bias2e) {
  int i = blockIdx.x * 256 + threadIdx.x;      // 168 blocks x 256 = 96*448 exactly
  if (i < 96 * KP) {
    int n = i / KP, kk = i - n * KP;
    int th = kk >> 6, q = kk & 63;
    int tw = q >> 3, c = q & 7;
    float s = 0.f;
    if (tw < 7) {
#pragma unroll 8
      for (int m = 0; m < 96; ++m)             // W2[(th*96+m)*96+n] * W1[(tw*8+c)*96+m]
        s += W2[(th * 96 + m) * 96 + n] * W1[(tw * 8 + c) * 96 + m];
    }
    wct[i] = f2bf(s);
  }
  if (i < 96) {
    float s = b2[i];
#pragma unroll 8
    for (int kc = 0; kc < 672; ++kc) {
      int m = kc - (kc / 96) * 96;
      s += W2[kc * 96 + i] * b1[m];
    }
    bias2e[i] = s;
  }
}

__global__ __launch_bounds__(NTHREADS, 4)      // 128-reg budget; live ~110
void conv7(const float* __restrict__ x, const unsigned short* __restrict__ wct,
           const float* __restrict__ bias2e, float* __restrict__ out) {
  __shared__ __align__(16) unsigned short xt[RS][XC][CIN];   // 13,376 B

  const int tid = threadIdx.x;
  const int w0  = blockIdx.x * TW;
  const int h0  = blockIdx.y * TH;
  const int b   = blockIdx.z;

  const int wid  = tid >> 6;        // wave id
  const int lane = tid & 63;
  const int l31  = lane & 31;       // A: ch-in-tile / B,D: pixel
  const int hi   = lane >> 5;       // k-half
  const int cht  = wid >> 1;        // channel tile 0..2 (32 ch each)
  const int rg   = wid & 1;         // row group 0..1 (8 rows each)
  const int ch   = cht * 32 + l31;  // A channel row

  // ---- stage x halo tile (symmetric pad applied), fp32 -> bf16 ----
  const float* xb = x + (size_t)b * H_ * W_ * CIN;
  for (int idx = tid; idx < RS * XC; idx += NTHREADS) {
    int rr = idx / XC, cc = idx - rr * XC;
    int hr = symH(h0 - 3 + rr);
    int wc = symW(w0 - 3 + cc);
    const float4* px = (const float4*)(xb + ((size_t)hr * W_ + wc) * CIN);
    float4 v0 = px[0], v1 = px[1];
    unsigned p0 = ((unsigned)f2bf(v0.y) << 16) | f2bf(v0.x);
    unsigned p1 = ((unsigned)f2bf(v0.w) << 16) | f2bf(v0.z);
    unsigned p2 = ((unsigned)f2bf(v1.y) << 16) | f2bf(v1.x);
    unsigned p3 = ((unsigned)f2bf(v1.w) << 16) | f2bf(v1.z);
    *(i32x4*)&xt[rr][cc][0] = (i32x4){(int)p0, (int)p1, (int)p2, (int)p3};
  }

  const unsigned short* wrow = wct + (size_t)ch * KP;
  const unsigned short* xtf  = &xt[0][0][0];

  __syncthreads();

#define ROWSTR (XC * CIN)            // 304 elements per staged row
  const int boff3 = 48;              // s2=3: tw=6 both halves (hi=1 weights are 0)
  const int twoff = 8 * hi;          // tw = 2*s2 + hi -> element off 16*s2 + 8*hi

  // weight frags for phase th: wrow[th*64 + 16*s2 + 8*hi]
#define WLOAD(dst, thv)                                                        \
  { _Pragma("unroll") for (int s = 0; s < 4; ++s)                              \
      (dst)[s] = ld16s(&wrow[(thv) * 64 + 16 * s + 8 * hi]); }

  // one phase: 4 slices x 4 rows; B at bp + {twoff,16+twoff,32+twoff,48}
#define PHASE(wf, bp)                                                          \
  { _Pragma("unroll") for (int s = 0; s < 4; ++s) {                            \
      const unsigned short* q_ = (bp) + (s == 3 ? boff3 : 16 * s + twoff);     \
      acc0 = mfma32((wf)[s], ld16s(q_), acc0);                                 \
      acc1 = mfma32((wf)[s], ld16s(q_ + ROWSTR), acc1);                        \
      acc2 = mfma32((wf)[s], ld16s(q_ + 2 * ROWSTR), acc2);                    \
      acc3 = mfma32((wf)[s], ld16s(q_ + 3 * ROWSTR), acc3);                    \
    } }

#pragma unroll 1
  for (int sub = 0; sub < 2; ++sub) {        // 4-row quad: m0..m0+3
    const int m0 = rg * 8 + sub * 4;
    f32x16 acc0 = {}, acc1 = {}, acc2 = {}, acc3 = {};
    const unsigned short* bp = xtf + m0 * ROWSTR + l31 * CIN;  // th = 0

    bf16x8 wa[4], wb[4];
    WLOAD(wa, 0)
#pragma unroll 1
    for (int pp = 0; pp < 3; ++pp) {         // phases {2pp, 2pp+1}
      WLOAD(wb, 2 * pp + 1)                  // prefetch next under compute
      PHASE(wa, bp)
      bp += ROWSTR;
      WLOAD(wa, 2 * pp + 2)
      PHASE(wb, bp)
      bp += ROWSTR;
    }
    PHASE(wa, bp)                            // th = 6 tail

    // ---- epilogue: PLAIN stores (L2 merges 32B halves into full lines) ----
#define EPI(R, ACC)                                                               \
    {                                                                             \
      const size_t ob = (((size_t)b * H_ + h0 + m0 + (R)) * W_ + w0 + l31) * COUT \
                        + cht * 32 + 4 * hi;                                      \
      _Pragma("unroll")                                                           \
      for (int q = 0; q < 4; ++q) {                                               \
        const float4 bia = *(const float4*)&bias2e[cht * 32 + 8 * q + 4 * hi];    \
        f32x4 v = {(ACC)[4 * q] + bia.x, (ACC)[4 * q + 1] + bia.y,                \
                   (ACC)[4 * q + 2] + bia.z, (ACC)[4 * q + 3] + bia.w};           \
        *(f32x4*)(out + ob + 8 * q) = v;                                          \
      }                                                                           \
    }
    EPI(0, acc0) EPI(1, acc1) EPI(2, acc2) EPI(3, acc3)
#undef EPI
  }
}

extern "C" void kernel_launch(void* const* d_in, const int* in_sizes, int n_in,
                              void* d_out, int out_size, void* d_ws, size_t ws_size,
                              hipStream_t stream) {
  const float* x  = (const float*)d_in[0];
  const float* W1 = (const float*)d_in[1];
  const float* b1 = (const float*)d_in[2];
  const float* W2 = (const float*)d_in[3];
  const float* b2 = (const float*)d_in[4];
  // d_in[5] = training (unused)

  unsigned short* wct = (unsigned short*)d_ws;       // 96*448 u16
  float* bias2e = (float*)(wct + 96 * KP);           // 96 f32
  float* out = (float*)d_out;

  prep_kernel<<<dim3(168), dim3(256), 0, stream>>>(W1, b1, W2, b2, wct, bias2e);
  conv7<<<dim3(W_ / TW, H_ / TH, B_), dim3(NTHREADS), 0, stream>>>(
      x, wct, bias2e, out);
}

// Round 17
// 262.891 us; speedup vs baseline: 1.7836x; 1.7836x over previous
//
#include <hip/hip_runtime.h>

// Stream_PreNet as ONE composed 7x7 conv (exact algebra, proven R11),
// 16x16x32 MFMA. R17 = R11 + 2 channel-tiles per wave: one B-fragment read
// feeds TWO MFMAs (acc0/acc1) -> LDS reads per output HALVE (R11's dominant
// cost, ~98us/CU -> ~49). Block = 16 rows x 16 px x 96ch; 6 waves =
// 2 row-groups x 3 ch-groups(32ch). Pass structure is R11's proven
// "load wf at pass top -> consume immediately" (R16's ping-pong prefetch
// spilled 1GB to scratch: source-level SW pipelining is CLOSED on this
// compiler). Passes {5,4,4} -> peak weight set 40 VGPR; live ~115;
// launch_bounds(384,3): cap ~170 (allocator headroom), 2 blocks/CU.
// Plain stores (NT = 2x write amplification, R13). Pair-49..51 zero-weight:
// g==0 reads pair 48 (valid), g>0 uses zero B (no OOB/NaN, R3 lesson).
// d_ws: wct (96*416 bf16 = 79,872B) + bias2e (96 f32) = 80,256 B.

#define B_   8
#define H_   512
#define W_   256
#define CIN  8
#define COUT 96
#define TH   16           // output rows per block
#define TW   16           // output cols per block
#define RS   (TH + 6)     // 22 staged x rows
#define XC   22           // staged x cols used (TW+6)
#define XCP  23           // padded col stride (keeps 16B alignment: (r*23+c)*16B)
#define KP   416          // padded K (13 slices of 32)
#define NTHREADS 384      // 6 waves

typedef __bf16 bf16x8 __attribute__((ext_vector_type(8)));
typedef float  f32x4  __attribute__((ext_vector_type(4)));
typedef int    i32x4  __attribute__((ext_vector_type(4)));

__device__ __forceinline__ unsigned short f2bf(float f) {
  unsigned u = __builtin_bit_cast(unsigned, f);
  u += 0x7FFFu + ((u >> 16) & 1u);   // RNE
  return (unsigned short)(u >> 16);
}

__device__ __forceinline__ bf16x8 ld16s(const unsigned short* p) {
  i32x4 t = *(const i32x4*)p;        // 16B load -> ds_read_b128 / dwordx4
  return __builtin_bit_cast(bf16x8, t);
}

__device__ __forceinline__ f32x4 mfma16(bf16x8 a, bf16x8 b, f32x4 c) {
  return __builtin_amdgcn_mfma_f32_16x16x32_bf16(a, b, c, 0, 0, 0);
}

// jnp.pad mode='symmetric': -1->0, -2->1 ; N->N-1, N+1->N-2
__device__ __forceinline__ int symH(int i) { return i < 0 ? -1 - i : (i >= H_ ? 2 * H_ - 1 - i : i); }
__device__ __forceinline__ int symW(int i) { return i < 0 ? -1 - i : (i >= W_ ? 2 * W_ - 1 - i : i); }

// ---- prep: compose Wc = W2(7x1) o W1(1x7) in fp32, cast once to bf16 ----
// wct[n][k], k = p*8 + c, p = th*7+tw (p>=49 zero).  bias2e = b2 + fold(b1).
__global__ void prep_kernel(const float* __restrict__ W1, const float* __restrict__ b1,
                            const float* __restrict__ W2, const float* __restrict__ b2,
                            unsigned short* __restrict__ wct, float* __restrict__ bias2e) {
  int i = blockIdx.x * 256 + threadIdx.x;      // 156 blocks x 256 = 96*416 exactly
  if (i < 96 * KP) {
    int n = i / KP, k = i - n * KP;
    int p = k >> 3, c = k & 7;
    float s = 0.f;
    if (p < 49) {
      int th = p / 7, tw = p - 7 * th;
#pragma unroll 8
      for (int m = 0; m < 96; ++m)             // W2[(th*96+m)*96+n] * W1[(tw*8+c)*96+m]
        s += W2[(th * 96 + m) * 96 + n] * W1[(tw * 8 + c) * 96 + m];
    }
    wct[i] = f2bf(s);
  }
  if (i < 96) {
    float s = b2[i];
#pragma unroll 8
    for (int kc = 0; kc < 672; ++kc) {
      int m = kc - (kc / 96) * 96;
      s += W2[kc * 96 + i] * b1[m];
    }
    bias2e[i] = s;
  }
}

__global__ __launch_bounds__(NTHREADS, 3)      // cap ~170; 2 blocks/CU
void conv7(const float* __restrict__ x, const unsigned short* __restrict__ wct,
           const float* __restrict__ bias2e, float* __restrict__ out) {
  __shared__ __align__(16) unsigned short xt[RS][XCP][CIN];   // 8,096 B

  const int tid = threadIdx.x;
  const int w0  = blockIdx.x * TW;
  const int h0  = blockIdx.y * TH;
  const int b   = blockIdx.z;

  const int wid  = tid >> 6;        // wave id
  const int lane = tid & 63;
  const int l15  = lane & 15;       // A: ch-in-tile / B,D: pixel
  const int g    = lane >> 4;       // k-group
  const int chg  = wid >> 1;        // ch group 0..2 (32 ch)
  const int rg   = wid & 1;         // row group 0..1 (8 rows)
  const int m0   = rg * 8;
  const int ch0  = chg * 32 + l15;  // A row, tile 0
  // tile 1 = ch0 + 16

  // ---- stage x halo tile (symmetric pad applied), fp32 -> bf16 ----
  const float* xb = x + (size_t)b * H_ * W_ * CIN;
  for (int idx = tid; idx < RS * XC; idx += NTHREADS) {
    int rr = idx / XC, cc = idx - rr * XC;
    int hr = symH(h0 - 3 + rr);
    int wc = symW(w0 - 3 + cc);
    const float4* px = (const float4*)(xb + ((size_t)hr * W_ + wc) * CIN);
    float4 v0 = px[0], v1 = px[1];
    unsigned p0 = ((unsigned)f2bf(v0.y) << 16) | f2bf(v0.x);
    unsigned p1 = ((unsigned)f2bf(v0.w) << 16) | f2bf(v0.z);
    unsigned p2 = ((unsigned)f2bf(v1.y) << 16) | f2bf(v1.x);
    unsigned p3 = ((unsigned)f2bf(v1.w) << 16) | f2bf(v1.z);
    *(i32x4*)&xt[rr][cc][0] = (i32x4){(int)p0, (int)p1, (int)p2, (int)p3};
  }

  const unsigned short* wrow0 = wct + (size_t)ch0 * KP;
  const unsigned short* wrow1 = wrow0 + (size_t)16 * KP;
  const unsigned short* xtf   = &xt[0][0][0];
  const i32x4 z4 = {0, 0, 0, 0};

  f32x4 acc0[8], acc1[8];
#pragma unroll
  for (int m = 0; m < 8; ++m) { acc0[m] = (f32x4){0,0,0,0}; acc1[m] = (f32x4){0,0,0,0}; }

  __syncthreads();

#define ROWSTR (XCP * CIN)           // 184 elements per staged row

  // one pass: NS slices from S0; weight frags loaded at top, consumed at once.
  // slice s, k-group g -> pair p=4s+g; th=p/7 (magic), tw=p%7.
  // B[k][n=pix l15] = xt[m0+m+th][l15+tw][c]; one read feeds acc0 AND acc1.
#define PASS(S0, NS, HAS_TAIL)                                                  \
  { bf16x8 wf0[NS], wf1[NS];                                                    \
    _Pragma("unroll") for (int s2 = 0; s2 < (NS); ++s2) {                       \
      wf0[s2] = ld16s(&wrow0[32 * ((S0) + s2) + 8 * g]);                        \
      wf1[s2] = ld16s(&wrow1[32 * ((S0) + s2) + 8 * g]);                        \
    }                                                                           \
    _Pragma("unroll") for (int s2 = 0; s2 < (NS); ++s2) {                       \
      int p = 4 * ((S0) + s2) + g;                                              \
      int pc = p > 48 ? 48 : p;                                                 \
      int th = (pc * 9363) >> 16;            /* /7 magic, exact for pc<=48 */   \
      int tw = pc - 7 * th;                                                     \
      const unsigned short* bp = xtf + (m0 + th) * ROWSTR + (l15 + tw) * CIN;   \
      const bool tail = (HAS_TAIL) && ((S0) + s2 == 12) && (g != 0);            \
      _Pragma("unroll") for (int m = 0; m < 8; ++m) {                           \
        bf16x8 xv = tail ? __builtin_bit_cast(bf16x8, z4)                       \
                         : ld16s(bp + m * ROWSTR);                              \
        acc0[m] = mfma16(wf0[s2], xv, acc0[m]);                                 \
        acc1[m] = mfma16(wf1[s2], xv, acc1[m]);                                 \
      }                                                                         \
    } }

#pragma unroll 1
  for (int pass = 0; pass < 3; ++pass) {
    if (pass == 0)      { PASS(0, 5, 0) }
    else if (pass == 1) { PASS(5, 4, 0) }
    else                { PASS(9, 4, 1) }
  }
#undef PASS

  // ---- epilogue: lane = pixel l15, channels chg*32 + {4g..4g+3, 16+4g..} ----
  const float4 bia0 = *(const float4*)&bias2e[chg * 32 + 4 * g];
  const float4 bia1 = *(const float4*)&bias2e[chg * 32 + 16 + 4 * g];
  const size_t ob0 = (((size_t)b * H_ + h0 + m0) * W_ + (w0 + l15)) * COUT + chg * 32 + 4 * g;
#pragma unroll
  for (int m = 0; m < 8; ++m) {
    f32x4 v0 = acc0[m], v1 = acc1[m];
    v0[0] += bia0.x; v0[1] += bia0.y; v0[2] += bia0.z; v0[3] += bia0.w;
    v1[0] += bia1.x; v1[1] += bia1.y; v1[2] += bia1.z; v1[3] += bia1.w;
    const size_t ob = ob0 + (size_t)m * (W_ * COUT);
    *(f32x4*)(out + ob)      = v0;
    *(f32x4*)(out + ob + 16) = v1;
  }
}

extern "C" void kernel_launch(void* const* d_in, const int* in_sizes, int n_in,
                              void* d_out, int out_size, void* d_ws, size_t ws_size,
                              hipStream_t stream) {
  const float* x  = (const float*)d_in[0];
  const float* W1 = (const float*)d_in[1];
  const float* b1 = (const float*)d_in[2];
  const float* W2 = (const float*)d_in[3];
  const float* b2 = (const float*)d_in[4];
  // d_in[5] = training (unused)

  unsigned short* wct = (unsigned short*)d_ws;       // 96*416 u16
  float* bias2e = (float*)(wct + 96 * KP);           // 96 f32
  float* out = (float*)d_out;

  prep_kernel<<<dim3(156), dim3(256), 0, stream>>>(W1, b1, W2, b2, wct, bias2e);
  conv7<<<dim3(W_ / TW, H_ / TH, B_), dim3(NTHREADS), 0, stream>>>(
      x, wct, bias2e, out);
}